// Round 2
// baseline (542.901 us; speedup 1.0000x reference)
//
#include <hip/hip_runtime.h>
#include <hip/hip_bf16.h>

#define N_ 32
#define CIN_ 64
#define COUT_ 64
#define RED_ 2
#define T_ 64
#define V_ 128
#define K_ 128  // RED_*T_

__device__ __forceinline__ float fast_tanhf(float x) {
    // tanh(x) = 1 - 2/(exp(2x)+1); exact at +-inf, branch-free
    float e = __expf(2.0f * x);
    float r = __builtin_amdgcn_rcpf(e + 1.0f);
    return 1.0f - 2.0f * r;
}

__device__ __forceinline__ unsigned short f2bf(float f) {
    __hip_bfloat16 h = __float2bfloat16(f);
    return *reinterpret_cast<unsigned short*>(&h);
}
__device__ __forceinline__ float bf2f(unsigned short u) {
    __hip_bfloat16 h = *reinterpret_cast<__hip_bfloat16*>(&u);
    return __bfloat162float(h);
}

// ---------------------------------------------------------------------------
// K1: fused 1x1 convs. Per block: one n, 256 contiguous tv positions.
// xf[n][o][tv] (bf16), a[n][k][v], b[n][k][v] (f32), k = r*64 + t.
// ---------------------------------------------------------------------------
__global__ __launch_bounds__(256) void k1_conv(
    const float* __restrict__ x,
    const float* __restrict__ Wf,  const float* __restrict__ bfv,
    const float* __restrict__ Wm1, const float* __restrict__ bm1,
    const float* __restrict__ Wm2, const float* __restrict__ bm2,
    unsigned short* __restrict__ xf, float* __restrict__ a, float* __restrict__ b)
{
    __shared__ float xt[CIN_][256];
    const int n   = blockIdx.x;
    const int tv0 = blockIdx.y * 256;
    const int tid = threadIdx.x;

    const float* xn = x + (size_t)n * CIN_ * (T_ * V_);
    for (int c = 0; c < CIN_; ++c)
        xt[c][tid] = xn[c * (T_ * V_) + tv0 + tid];
    __syncthreads();

    float accf[COUT_];
    #pragma unroll
    for (int o = 0; o < COUT_; ++o) accf[o] = bfv[o];
    float a1_0 = bm1[0], a1_1 = bm1[1];
    float a2_0 = bm2[0], a2_1 = bm2[1];

    #pragma unroll 4
    for (int c = 0; c < CIN_; ++c) {
        float xc = xt[c][tid];
        #pragma unroll
        for (int o = 0; o < COUT_; ++o)
            accf[o] = fmaf(Wf[o * CIN_ + c], xc, accf[o]);  // Wf index uniform -> s_load
        a1_0 = fmaf(Wm1[c],        xc, a1_0);
        a1_1 = fmaf(Wm1[CIN_ + c], xc, a1_1);
        a2_0 = fmaf(Wm2[c],        xc, a2_0);
        a2_1 = fmaf(Wm2[CIN_ + c], xc, a2_1);
    }

    const int tv = tv0 + tid;
    #pragma unroll 8
    for (int o = 0; o < COUT_; ++o)
        xf[((size_t)n * COUT_ + o) * (T_ * V_) + tv] = f2bf(accf[o]);

    const int t = tv >> 7, v = tv & 127;
    a[((size_t)n * K_ + t)       * V_ + v] = a1_0;
    a[((size_t)n * K_ + T_ + t)  * V_ + v] = a1_1;
    b[((size_t)n * K_ + t)       * V_ + v] = a2_0;
    b[((size_t)n * K_ + T_ + t)  * V_ + v] = a2_1;
}

// ---------------------------------------------------------------------------
// K2: xm[n][o][v][w] = sum_k Wrm[o][k]*tanh(a[n][k][v]-b[n][k][w]) + brm[o] + A[o][v][w]
// Each thread: one v, 4 consecutive w, 16 o's (o-quarter = wave id).
// Every tanh computed exactly once globally.
// ---------------------------------------------------------------------------
__global__ __launch_bounds__(256) void k2_xm(
    const float* __restrict__ a, const float* __restrict__ bsrc,
    const float* __restrict__ Wrm, const float* __restrict__ brm,
    const float* __restrict__ Amat, unsigned short* __restrict__ xm)
{
    __shared__ float wt[K_][COUT_];  // wt[k][o] = Wrm[o][k], 32 KB
    const int tid = threadIdx.x;
    for (int i = tid; i < K_ * COUT_; i += 256) {
        int k = i >> 6, o = i & 63;
        wt[k][o] = Wrm[o * K_ + k];  // uncoalesced 32KB read (L2), conflict-free LDS write
    }
    __syncthreads();

    const int n    = blockIdx.x;        // 32
    const int vp   = blockIdx.y;        // 64 v-pairs
    const int lane = tid & 63;
    const int oq   = tid >> 6;          // wave id = o-quarter, wave-uniform
    const int v    = vp * 2 + (lane >> 5);
    const int w    = (lane & 31) * 4;

    const float* an = a    + (size_t)n * K_ * V_;
    const float* bn = bsrc + (size_t)n * K_ * V_;

    float acc[16][4];
    #pragma unroll
    for (int j = 0; j < 16; ++j) {
        acc[j][0] = 0.f; acc[j][1] = 0.f; acc[j][2] = 0.f; acc[j][3] = 0.f;
    }

    #pragma unroll 2
    for (int k = 0; k < K_; ++k) {
        float  av = an[k * V_ + v];
        float4 bv = *reinterpret_cast<const float4*>(&bn[k * V_ + w]);
        float t0 = fast_tanhf(av - bv.x);
        float t1 = fast_tanhf(av - bv.y);
        float t2 = fast_tanhf(av - bv.z);
        float t3 = fast_tanhf(av - bv.w);
        const float* wrow = &wt[k][oq * 16];   // wave-uniform addr -> broadcast ds_read
        #pragma unroll
        for (int j = 0; j < 16; ++j) {
            float wv = wrow[j];
            acc[j][0] = fmaf(wv, t0, acc[j][0]);
            acc[j][1] = fmaf(wv, t1, acc[j][1]);
            acc[j][2] = fmaf(wv, t2, acc[j][2]);
            acc[j][3] = fmaf(wv, t3, acc[j][3]);
        }
    }

    #pragma unroll
    for (int j = 0; j < 16; ++j) {
        const int o = oq * 16 + j;
        const float br = brm[o];
        const float4 Av = *reinterpret_cast<const float4*>(&Amat[((size_t)o * V_ + v) * V_ + w]);
        ushort4 pk;
        pk.x = f2bf(acc[j][0] + br + Av.x);
        pk.y = f2bf(acc[j][1] + br + Av.y);
        pk.z = f2bf(acc[j][2] + br + Av.z);
        pk.w = f2bf(acc[j][3] + br + Av.w);
        *reinterpret_cast<ushort4*>(&xm[(((size_t)n * COUT_ + o) * V_ + v) * V_ + w]) = pk;
    }
}

// ---------------------------------------------------------------------------
// K3: out[n][c][t][w] = sum_v xf[n][c][t][v] * xm[n][t][v][w]
// One block per (n,t); xf tile transposed in LDS (padded), xm tile in LDS.
// Thread tile: 4c x 8w, all-float4 LDS reads.
// ---------------------------------------------------------------------------
__global__ __launch_bounds__(256) void k3_gemm(
    const unsigned short* __restrict__ xf,
    const unsigned short* __restrict__ xm,
    float* __restrict__ out)
{
    __shared__ float xfT[V_][68];   // [v][c], pad 68 keeps 16B align + breaks conflicts
    __shared__ float xmt[V_][V_];   // [v][w]
    const int n = blockIdx.x, t = blockIdx.y;
    const int tid = threadIdx.x;

    for (int i = tid; i < COUT_ * V_; i += 256) {
        int c = i >> 7, v = i & 127;
        xfT[v][c] = bf2f(xf[(((size_t)n * COUT_ + c) * T_ + t) * V_ + v]);
    }
    const unsigned short* xmb = xm + ((size_t)n * COUT_ + t) * V_ * V_;
    for (int i4 = tid * 4; i4 < V_ * V_; i4 += 1024) {
        ushort4 u = *reinterpret_cast<const ushort4*>(&xmb[i4]);
        int v = i4 >> 7, w = i4 & 127;
        xmt[v][w]     = bf2f(u.x);
        xmt[v][w + 1] = bf2f(u.y);
        xmt[v][w + 2] = bf2f(u.z);
        xmt[v][w + 3] = bf2f(u.w);
    }
    __syncthreads();

    const int c0 = (tid >> 4) * 4;
    const int w0 = (tid & 15) * 8;
    float acc[4][8];
    #pragma unroll
    for (int j = 0; j < 4; ++j)
        #pragma unroll
        for (int e = 0; e < 8; ++e) acc[j][e] = 0.f;

    #pragma unroll 2
    for (int v = 0; v < V_; ++v) {
        float4 xa = *reinterpret_cast<const float4*>(&xfT[v][c0]);
        float4 ma = *reinterpret_cast<const float4*>(&xmt[v][w0]);
        float4 mb = *reinterpret_cast<const float4*>(&xmt[v][w0 + 4]);
        float xc[4] = {xa.x, xa.y, xa.z, xa.w};
        float mv[8] = {ma.x, ma.y, ma.z, ma.w, mb.x, mb.y, mb.z, mb.w};
        #pragma unroll
        for (int j = 0; j < 4; ++j)
            #pragma unroll
            for (int e = 0; e < 8; ++e)
                acc[j][e] = fmaf(xc[j], mv[e], acc[j][e]);
    }

    #pragma unroll
    for (int j = 0; j < 4; ++j) {
        size_t base = (((size_t)n * COUT_ + (c0 + j)) * T_ + t) * V_;
        float4 o1 = make_float4(acc[j][0], acc[j][1], acc[j][2], acc[j][3]);
        float4 o2 = make_float4(acc[j][4], acc[j][5], acc[j][6], acc[j][7]);
        *reinterpret_cast<float4*>(&out[base + w0])     = o1;
        *reinterpret_cast<float4*>(&out[base + w0 + 4]) = o2;
    }
}

extern "C" void kernel_launch(void* const* d_in, const int* in_sizes, int n_in,
                              void* d_out, int out_size, void* d_ws, size_t ws_size,
                              hipStream_t stream) {
    const float* x   = (const float*)d_in[0];
    const float* A   = (const float*)d_in[1];
    const float* Wf  = (const float*)d_in[2];
    const float* bf  = (const float*)d_in[3];
    const float* Wm1 = (const float*)d_in[4];
    const float* bm1 = (const float*)d_in[5];
    const float* Wm2 = (const float*)d_in[6];
    const float* bm2 = (const float*)d_in[7];
    const float* Wrm = (const float*)d_in[8];
    const float* brm = (const float*)d_in[9];
    float* out = (float*)d_out;

    char* ws = (char*)d_ws;
    unsigned short* xf = (unsigned short*)ws;                       // 32*64*8192 bf16 = 32 MB
    size_t off = (size_t)N_ * COUT_ * T_ * V_ * 2;
    float* a = (float*)(ws + off); off += (size_t)N_ * K_ * V_ * 4; // 2 MB
    float* b = (float*)(ws + off); off += (size_t)N_ * K_ * V_ * 4; // 2 MB
    unsigned short* xm = (unsigned short*)(ws + off);               // 64 MB

    k1_conv<<<dim3(N_, (T_ * V_) / 256), 256, 0, stream>>>(
        x, Wf, bf, Wm1, bm1, Wm2, bm2, xf, a, b);
    k2_xm<<<dim3(N_, V_ / 2), 256, 0, stream>>>(a, b, Wrm, brm, A, xm);
    k3_gemm<<<dim3(N_, T_), 256, 0, stream>>>(xf, xm, out);
}

// Round 3
// 332.042 us; speedup vs baseline: 1.6350x; 1.6350x over previous
//
#include <hip/hip_runtime.h>
#include <hip/hip_bf16.h>

#define N_ 32
#define CIN_ 64
#define COUT_ 64
#define T_ 64
#define V_ 128
#define K_ 128  // RED_*T_

typedef __attribute__((ext_vector_type(8))) short short8v;  // 8 bf16 = 4 VGPR
typedef __attribute__((ext_vector_type(4))) short short4v;  // 4 bf16 = 2 VGPR
typedef __attribute__((ext_vector_type(4))) float f32x4;    // MFMA acc

__device__ __forceinline__ float fast_tanhf(float x) {
    // tanh(x) = 1 - 2/(exp(2x)+1); exact at +-inf, branch-free
    float e = __expf(2.0f * x);
    return 1.0f - 2.0f * __builtin_amdgcn_rcpf(e + 1.0f);
}
__device__ __forceinline__ unsigned short f2bf(float f) {
    __hip_bfloat16 h = __float2bfloat16(f);
    return *reinterpret_cast<unsigned short*>(&h);
}

// ---------------------------------------------------------------------------
// k0: AT[o][w][v] = A[o][v][w]  (4 MB, tiled 32x32 LDS transpose)
// ---------------------------------------------------------------------------
__global__ __launch_bounds__(256) void k0_transpose_A(
    const float* __restrict__ A, float* __restrict__ AT)
{
    __shared__ float t[32][33];
    const int o  = blockIdx.x;
    const int v0 = (blockIdx.y >> 2) * 32, w0 = (blockIdx.y & 3) * 32;
    const float* Ao = A  + (size_t)o * (V_ * V_);
    float*      ATo = AT + (size_t)o * (V_ * V_);
    for (int i = threadIdx.x; i < 1024; i += 256) {
        int r = i >> 5, c = i & 31;
        t[r][c] = Ao[(v0 + r) * V_ + (w0 + c)];
    }
    __syncthreads();
    for (int i = threadIdx.x; i < 1024; i += 256) {
        int r = i >> 5, c = i & 31;
        ATo[(w0 + r) * V_ + (v0 + c)] = t[c][r];
    }
}

// ---------------------------------------------------------------------------
// k1: 1x1 convs. o-chunks of 16 accs (prevents the fission that hit round-2's
// 64-acc version: VGPR=52 proved the compiler split the k-loop).
// Outputs: xf[n][o][t][v] bf16; aT[n][v][k] f32 (k-contig for k2 frag loads);
//          b[n][k][w] f32.
// ---------------------------------------------------------------------------
__global__ __launch_bounds__(256) void k1_conv(
    const float* __restrict__ x,
    const float* __restrict__ Wf,  const float* __restrict__ bfv,
    const float* __restrict__ Wm1, const float* __restrict__ bm1,
    const float* __restrict__ Wm2, const float* __restrict__ bm2,
    unsigned short* __restrict__ xf, float* __restrict__ aT, float* __restrict__ b)
{
    __shared__ float xt[CIN_][256];
    const int n = blockIdx.x, tv0 = blockIdx.y * 256, tid = threadIdx.x;
    const float* xn = x + (size_t)n * CIN_ * (T_ * V_);
    for (int c = 0; c < CIN_; ++c)
        xt[c][tid] = xn[c * (T_ * V_) + tv0 + tid];
    __syncthreads();
    const int tv = tv0 + tid;

    for (int oc = 0; oc < 4; ++oc) {
        float acc[16];
        #pragma unroll
        for (int j = 0; j < 16; ++j) acc[j] = bfv[oc * 16 + j];
        #pragma unroll 4
        for (int c = 0; c < CIN_; ++c) {
            float xc = xt[c][tid];
            #pragma unroll
            for (int j = 0; j < 16; ++j)
                acc[j] = fmaf(Wf[(oc * 16 + j) * CIN_ + c], xc, acc[j]);  // uniform -> s_load
        }
        #pragma unroll
        for (int j = 0; j < 16; ++j)
            xf[((size_t)n * COUT_ + oc * 16 + j) * (T_ * V_) + tv] = f2bf(acc[j]);
    }

    float a10 = bm1[0], a11 = bm1[1], a20 = bm2[0], a21 = bm2[1];
    #pragma unroll 4
    for (int c = 0; c < CIN_; ++c) {
        float xc = xt[c][tid];
        a10 = fmaf(Wm1[c],        xc, a10);
        a11 = fmaf(Wm1[CIN_ + c], xc, a11);
        a20 = fmaf(Wm2[c],        xc, a20);
        a21 = fmaf(Wm2[CIN_ + c], xc, a21);
    }
    const int t = tv >> 7, v = tv & 127;
    aT[((size_t)n * V_ + v) * K_ + t]       = a10;  // k = t
    aT[((size_t)n * V_ + v) * K_ + 64 + t]  = a11;  // k = 64+t
    b [((size_t)n * K_ + t) * V_ + v]       = a20;
    b [((size_t)n * K_ + 64 + t) * V_ + v]  = a21;
}

// ---------------------------------------------------------------------------
// k2: MFMA. Per block (n, w): C'[o][v] = sum_k Wrm[o][k] * tanh(b[k][w]-a[k][v])
// (note tanh(a-b) = -tanh(b-a); sign fixed in epilogue).
// xmT[n][o][w][v] = brm[o] + A[o][v][w] - C'[o][v].
// Wave: 64 o x 32 v (8 acc frags). k-mapping mu(g,j) = {4g+j, 16+4g+j} used
// identically for A(Wrm) and B(tanh) frags -> correct for any true HW bijection.
// ---------------------------------------------------------------------------
__global__ __launch_bounds__(256) void k2_mfma(
    const float* __restrict__ aT, const float* __restrict__ b,
    const float* __restrict__ Wrm, const float* __restrict__ brm,
    const float* __restrict__ AT, unsigned short* __restrict__ xmT)
{
    __shared__ float tile[COUT_][V_ + 1];  // [o][v], stride 129 breaks conflicts
    __shared__ float bcol[K_];
    const int n = blockIdx.x, w = blockIdx.y;
    const int tid  = threadIdx.x;
    const int lane = tid & 63, wid = tid >> 6;
    const int l15  = lane & 15, g = lane >> 4;

    if (tid < K_) bcol[tid] = b[((size_t)n * K_ + tid) * V_ + w];

    // Wrm A-frags, VGPR-resident: o = ot*16+l15, k = kc*32 + mu(g,j)
    short8v wf[4][4];
    #pragma unroll
    for (int ot = 0; ot < 4; ++ot) {
        const float* wr = Wrm + (size_t)(ot * 16 + l15) * K_;
        #pragma unroll
        for (int kc = 0; kc < 4; ++kc) {
            const float* p = wr + kc * 32 + 4 * g;
            float4 lo = *reinterpret_cast<const float4*>(p);
            float4 hi = *reinterpret_cast<const float4*>(p + 16);
            short8v f;
            f[0] = (short)f2bf(lo.x); f[1] = (short)f2bf(lo.y);
            f[2] = (short)f2bf(lo.z); f[3] = (short)f2bf(lo.w);
            f[4] = (short)f2bf(hi.x); f[5] = (short)f2bf(hi.y);
            f[6] = (short)f2bf(hi.z); f[7] = (short)f2bf(hi.w);
            wf[ot][kc] = f;
        }
    }
    __syncthreads();  // bcol ready

    const float* aTn = aT + (size_t)n * V_ * K_;
    f32x4 acc[4][2];
    #pragma unroll
    for (int ot = 0; ot < 4; ++ot)
        #pragma unroll
        for (int vt = 0; vt < 2; ++vt)
            acc[ot][vt] = (f32x4){0.f, 0.f, 0.f, 0.f};

    #pragma unroll
    for (int vt = 0; vt < 2; ++vt) {
        const int v = wid * 32 + vt * 16 + l15;
        const float* ar = aTn + (size_t)v * K_;
        #pragma unroll
        for (int kc = 0; kc < 4; ++kc) {
            const int k0 = kc * 32 + 4 * g;
            float4 alo = *reinterpret_cast<const float4*>(ar + k0);
            float4 ahi = *reinterpret_cast<const float4*>(ar + k0 + 16);
            float4 blo = *reinterpret_cast<const float4*>(&bcol[k0]);
            float4 bhi = *reinterpret_cast<const float4*>(&bcol[k0 + 16]);
            short8v e;
            e[0] = (short)f2bf(fast_tanhf(blo.x - alo.x));
            e[1] = (short)f2bf(fast_tanhf(blo.y - alo.y));
            e[2] = (short)f2bf(fast_tanhf(blo.z - alo.z));
            e[3] = (short)f2bf(fast_tanhf(blo.w - alo.w));
            e[4] = (short)f2bf(fast_tanhf(bhi.x - ahi.x));
            e[5] = (short)f2bf(fast_tanhf(bhi.y - ahi.y));
            e[6] = (short)f2bf(fast_tanhf(bhi.z - ahi.z));
            e[7] = (short)f2bf(fast_tanhf(bhi.w - ahi.w));
            #pragma unroll
            for (int ot = 0; ot < 4; ++ot)
                acc[ot][vt] = __builtin_amdgcn_mfma_f32_16x16x32_bf16(
                    wf[ot][kc], e, acc[ot][vt], 0, 0, 0);
        }
    }

    // acc -> LDS tile (C/D layout: row = 4g+r, col = l15)
    #pragma unroll
    for (int ot = 0; ot < 4; ++ot)
        #pragma unroll
        for (int vt = 0; vt < 2; ++vt)
            #pragma unroll
            for (int r = 0; r < 4; ++r)
                tile[ot * 16 + 4 * g + r][wid * 32 + vt * 16 + l15] = acc[ot][vt][r];
    __syncthreads();

    // coalesced dump: xmT[n][o][w][v] = brm[o] + AT[o][w][v] - tile[o][v]
    for (int i = tid; i < COUT_ * 64; i += 256) {
        int o = i >> 6, vp = i & 63;
        float t0 = tile[o][2 * vp], t1 = tile[o][2 * vp + 1];
        float2 at = *reinterpret_cast<const float2*>(
            AT + ((size_t)o * V_ + w) * V_ + 2 * vp);
        float br = brm[o];
        unsigned u = (unsigned)f2bf(br + at.x - t0)
                   | ((unsigned)f2bf(br + at.y - t1) << 16);
        reinterpret_cast<unsigned*>(xmT)[(((size_t)n * COUT_ + o) * V_ + w) * 64 + vp] = u;
    }
}

// ---------------------------------------------------------------------------
// k3: MFMA. Per block (n, t): out[c][w] = sum_v xf[c][v] * xmT[t][w][v].
// Both tiles LDS-staged with T2 XOR-swizzle ((row&7)<<4 on byte offset) so
// frag reads (16 lanes at 256B row stride) don't 16-way bank-conflict.
// Output f32 -> accumulators store directly, 64B-coalesced per 16-lane group.
// ---------------------------------------------------------------------------
__global__ __launch_bounds__(256) void k3_mfma(
    const unsigned short* __restrict__ xf,
    const unsigned short* __restrict__ xmT,
    float* __restrict__ out)
{
    __shared__ unsigned short xfl[COUT_ * V_];  // [c][v] swizzled, 16 KB
    __shared__ unsigned short xml[V_ * V_];     // [w][v] swizzled, 32 KB
    const int n = blockIdx.x, t = blockIdx.y;
    const int tid  = threadIdx.x;
    const int lane = tid & 63, wid = tid >> 6;
    const int l15  = lane & 15, g = lane >> 4;

    for (int i = tid; i < 1024; i += 256) {  // xf tile, 16B chunks
        int c = i >> 4, ch = i & 15;
        float4 d = *reinterpret_cast<const float4*>(
            xf + (((size_t)n * COUT_ + c) * T_ + t) * V_ + ch * 8);
        int dst = c * 256 + ((ch * 16) ^ ((c & 7) << 4));
        *reinterpret_cast<float4*>(reinterpret_cast<char*>(xfl) + dst) = d;
    }
    for (int i = tid; i < 2048; i += 256) {  // xm tile
        int wq = i >> 4, ch = i & 15;
        float4 d = *reinterpret_cast<const float4*>(
            xmT + (((size_t)n * COUT_ + t) * V_ + wq) * V_ + ch * 8);
        int dst = wq * 256 + ((ch * 16) ^ ((wq & 7) << 4));
        *reinterpret_cast<float4*>(reinterpret_cast<char*>(xml) + dst) = d;
    }
    __syncthreads();

    f32x4 acc[4][2];
    #pragma unroll
    for (int ct = 0; ct < 4; ++ct)
        #pragma unroll
        for (int wt = 0; wt < 2; ++wt)
            acc[ct][wt] = (f32x4){0.f, 0.f, 0.f, 0.f};

    #pragma unroll
    for (int kc = 0; kc < 4; ++kc) {
        const int vb0 = (kc * 32 + 4 * g) * 2;  // byte offset, half 0
        const int vb1 = vb0 + 32;               // +16 elements
        short8v af[4];
        #pragma unroll
        for (int ct = 0; ct < 4; ++ct) {
            int c = ct * 16 + l15, sw = (c & 7) << 4;
            short4v lo = *reinterpret_cast<const short4v*>(
                reinterpret_cast<const char*>(xfl) + c * 256 + (vb0 ^ sw));
            short4v hi = *reinterpret_cast<const short4v*>(
                reinterpret_cast<const char*>(xfl) + c * 256 + (vb1 ^ sw));
            af[ct] = __builtin_shufflevector(lo, hi, 0, 1, 2, 3, 4, 5, 6, 7);
        }
        short8v bg[2];
        #pragma unroll
        for (int wt = 0; wt < 2; ++wt) {
            int wq = wid * 32 + wt * 16 + l15, sw = (wq & 7) << 4;
            short4v lo = *reinterpret_cast<const short4v*>(
                reinterpret_cast<const char*>(xml) + wq * 256 + (vb0 ^ sw));
            short4v hi = *reinterpret_cast<const short4v*>(
                reinterpret_cast<const char*>(xml) + wq * 256 + (vb1 ^ sw));
            bg[wt] = __builtin_shufflevector(lo, hi, 0, 1, 2, 3, 4, 5, 6, 7);
        }
        #pragma unroll
        for (int ct = 0; ct < 4; ++ct)
            #pragma unroll
            for (int wt = 0; wt < 2; ++wt)
                acc[ct][wt] = __builtin_amdgcn_mfma_f32_16x16x32_bf16(
                    af[ct], bg[wt], acc[ct][wt], 0, 0, 0);
    }

    #pragma unroll
    for (int ct = 0; ct < 4; ++ct)
        #pragma unroll
        for (int wt = 0; wt < 2; ++wt)
            #pragma unroll
            for (int r = 0; r < 4; ++r) {
                int c = ct * 16 + 4 * g + r;
                int wcol = wid * 32 + wt * 16 + l15;
                out[(((size_t)n * COUT_ + c) * T_ + t) * V_ + wcol] = acc[ct][wt][r];
            }
}

extern "C" void kernel_launch(void* const* d_in, const int* in_sizes, int n_in,
                              void* d_out, int out_size, void* d_ws, size_t ws_size,
                              hipStream_t stream) {
    const float* x   = (const float*)d_in[0];
    const float* A   = (const float*)d_in[1];
    const float* Wf  = (const float*)d_in[2];
    const float* bf  = (const float*)d_in[3];
    const float* Wm1 = (const float*)d_in[4];
    const float* bm1 = (const float*)d_in[5];
    const float* Wm2 = (const float*)d_in[6];
    const float* bm2 = (const float*)d_in[7];
    const float* Wrm = (const float*)d_in[8];
    const float* brm = (const float*)d_in[9];
    float* out = (float*)d_out;

    char* ws = (char*)d_ws;
    unsigned short* xf = (unsigned short*)ws;            // 33,554,432 B
    size_t off = (size_t)N_ * COUT_ * T_ * V_ * 2;
    float* b   = (float*)(ws + off); off += (size_t)N_ * K_ * V_ * 4;   // 2 MB
    float* aT  = (float*)(ws + off); off += (size_t)N_ * V_ * K_ * 4;   // 2 MB
    float* AT  = (float*)(ws + off); off += (size_t)COUT_ * V_ * V_ * 4;// 4 MB
    unsigned short* xmT = (unsigned short*)(ws + off);   // 64 MB

    k0_transpose_A<<<dim3(COUT_, 16), 256, 0, stream>>>(A, AT);
    k1_conv<<<dim3(N_, (T_ * V_) / 256), 256, 0, stream>>>(
        x, Wf, bf, Wm1, bm1, Wm2, bm2, xf, aT, b);
    k2_mfma<<<dim3(N_, V_), 256, 0, stream>>>(aT, b, Wrm, brm, AT, xmT);
    k3_mfma<<<dim3(N_, T_), 256, 0, stream>>>(xf, xmT, out);
}

// Round 4
// 270.685 us; speedup vs baseline: 2.0057x; 1.2267x over previous
//
#include <hip/hip_runtime.h>
#include <hip/hip_bf16.h>

#define N_ 32
#define CIN_ 64
#define COUT_ 64
#define T_ 64
#define V_ 128
#define K_ 128  // RED_*T_

typedef __attribute__((ext_vector_type(8))) short short8v;  // 8 bf16 = 4 VGPR
typedef __attribute__((ext_vector_type(4))) short short4v;  // 4 bf16 = 2 VGPR
typedef __attribute__((ext_vector_type(4))) float f32x4;    // MFMA acc

__device__ __forceinline__ float fast_tanhf(float x) {
    // tanh(x) = 1 - 2/(exp(2x)+1); exact at +-inf, branch-free
    float e = __expf(2.0f * x);
    return 1.0f - 2.0f * __builtin_amdgcn_rcpf(e + 1.0f);
}
__device__ __forceinline__ unsigned short f2bf(float f) {
    __hip_bfloat16 h = __float2bfloat16(f);
    return *reinterpret_cast<unsigned short*>(&h);
}

// ---------------------------------------------------------------------------
// k0a: AT[o][w][v] = A[o][v][w]  (4 MB, tiled 32x32 LDS transpose)
// ---------------------------------------------------------------------------
__global__ __launch_bounds__(256) void k0_transpose_A(
    const float* __restrict__ A, float* __restrict__ AT)
{
    __shared__ float t[32][33];
    const int o  = blockIdx.x;
    const int v0 = (blockIdx.y >> 2) * 32, w0 = (blockIdx.y & 3) * 32;
    const float* Ao = A  + (size_t)o * (V_ * V_);
    float*      ATo = AT + (size_t)o * (V_ * V_);
    for (int i = threadIdx.x; i < 1024; i += 256) {
        int r = i >> 5, c = i & 31;
        t[r][c] = Ao[(v0 + r) * V_ + (w0 + c)];
    }
    __syncthreads();
    for (int i = threadIdx.x; i < 1024; i += 256) {
        int r = i >> 5, c = i & 31;
        ATo[(w0 + r) * V_ + (v0 + c)] = t[c][r];
    }
}

// ---------------------------------------------------------------------------
// k0b: Wrm -> lane-ordered bf16 A-fragment table (16 KB).
// Entry (ot,kc,lane): o = ot*16+l15, k(j) = kc*32 + 4g + (j<4 ? j : 12+j).
// k2 then loads fragments as contiguous 16B/lane (1 KiB per wave instr).
// ---------------------------------------------------------------------------
__global__ __launch_bounds__(256) void k0b_wrm_frag(
    const float* __restrict__ Wrm, unsigned short* __restrict__ wfrag)
{
    const int ent = blockIdx.x * 256 + threadIdx.x;  // 1024 entries
    const int lane = ent & 63, kc = (ent >> 6) & 3, ot = ent >> 8;
    const int l15 = lane & 15, g = lane >> 4;
    const float* wr = Wrm + (size_t)(ot * 16 + l15) * K_ + kc * 32 + 4 * g;
    short8v f;
    #pragma unroll
    for (int j = 0; j < 4; ++j) f[j]     = (short)f2bf(wr[j]);
    #pragma unroll
    for (int j = 0; j < 4; ++j) f[4 + j] = (short)f2bf(wr[16 + j]);
    reinterpret_cast<short8v*>(wfrag)[ent] = f;
}

// ---------------------------------------------------------------------------
// k1: 1x1 convs (o-chunked to avoid loop fission). Outputs:
//   xf[n][o][t][v] bf16
//   a_til[n][v>>4][k][v&15] f32  (k2 E-frag dword loads come out coalesced)
//   bT[n][w][k] f32              (k2 b loads contiguous/broadcast)
// ---------------------------------------------------------------------------
__global__ __launch_bounds__(256) void k1_conv(
    const float* __restrict__ x,
    const float* __restrict__ Wf,  const float* __restrict__ bfv,
    const float* __restrict__ Wm1, const float* __restrict__ bm1,
    const float* __restrict__ Wm2, const float* __restrict__ bm2,
    unsigned short* __restrict__ xf, float* __restrict__ a_til,
    float* __restrict__ bT)
{
    __shared__ float xt[CIN_][256];
    const int n = blockIdx.x, tv0 = blockIdx.y * 256, tid = threadIdx.x;
    const float* xn = x + (size_t)n * CIN_ * (T_ * V_);
    for (int c = 0; c < CIN_; ++c)
        xt[c][tid] = xn[c * (T_ * V_) + tv0 + tid];
    __syncthreads();
    const int tv = tv0 + tid;

    for (int oc = 0; oc < 4; ++oc) {
        float acc[16];
        #pragma unroll
        for (int j = 0; j < 16; ++j) acc[j] = bfv[oc * 16 + j];
        #pragma unroll 4
        for (int c = 0; c < CIN_; ++c) {
            float xc = xt[c][tid];
            #pragma unroll
            for (int j = 0; j < 16; ++j)
                acc[j] = fmaf(Wf[(oc * 16 + j) * CIN_ + c], xc, acc[j]);  // uniform -> s_load
        }
        #pragma unroll
        for (int j = 0; j < 16; ++j)
            xf[((size_t)n * COUT_ + oc * 16 + j) * (T_ * V_) + tv] = f2bf(acc[j]);
    }

    float a10 = bm1[0], a11 = bm1[1], a20 = bm2[0], a21 = bm2[1];
    #pragma unroll 4
    for (int c = 0; c < CIN_; ++c) {
        float xc = xt[c][tid];
        a10 = fmaf(Wm1[c],        xc, a10);
        a11 = fmaf(Wm1[CIN_ + c], xc, a11);
        a20 = fmaf(Wm2[c],        xc, a20);
        a21 = fmaf(Wm2[CIN_ + c], xc, a21);
    }
    const int t = tv >> 7, v = tv & 127;
    // a_til: ((n*8 + v/16)*128 + k)*16 + v%16 ; k = t and 64+t  (coalesced 64B chunks)
    float* at = a_til + (((size_t)n * 8 + (v >> 4)) * K_) * 16 + (v & 15);
    at[(size_t)t * 16]        = a10;
    at[(size_t)(64 + t) * 16] = a11;
    // bT[n][w=v][k] ; k = t and 64+t  (strided 4B scatter, small total)
    float* btp = bT + ((size_t)n * V_ + v) * K_;
    btp[t]      = a20;
    btp[64 + t] = a21;
}

// ---------------------------------------------------------------------------
// k2: MFMA. Per block (n, w): C'[o][v] = sum_k Wrm[o][k] * tanh(b[k][w]-a[k][v])
// xmT[n][o][w][v] = brm[o] + A[o][v][w] - C'[o][v]   (tanh odd => sign trick).
// Phase 1: build 8 E-frags from coalesced a_til dwords + broadcast bT float4s.
// Phase 2: stream wfrag (contiguous, L1-hit) through 32 MFMAs.
// No syncthreads until the epilogue tile dump.
// ---------------------------------------------------------------------------
__global__ __launch_bounds__(256) void k2_mfma(
    const float* __restrict__ a_til, const float* __restrict__ bT,
    const unsigned short* __restrict__ wfrag, const float* __restrict__ brm,
    const float* __restrict__ AT, unsigned short* __restrict__ xmT)
{
    __shared__ float tile[COUT_][V_ + 1];  // [o][v], stride 129 (2-way = free)
    const int n = blockIdx.x, w = blockIdx.y;
    const int tid  = threadIdx.x;
    const int lane = tid & 63, wid = tid >> 6;
    const int l15  = lane & 15, g = lane >> 4;

    const float* bt = bT + ((size_t)n * V_ + w) * K_;
    const float* abase = a_til + (size_t)n * 16384 + l15;  // + vb*2048 + k*16

    // Phase 1: E-fragments (each tanh computed exactly once globally)
    short8v e[2][4];
    #pragma unroll
    for (int vt = 0; vt < 2; ++vt) {
        const float* ap = abase + (size_t)(wid * 2 + vt) * 2048;
        #pragma unroll
        for (int kc = 0; kc < 4; ++kc) {
            const int k0 = kc * 32 + 4 * g;
            float4 bl = *reinterpret_cast<const float4*>(bt + k0);
            float4 bh = *reinterpret_cast<const float4*>(bt + k0 + 16);
            short8v t;
            t[0] = (short)f2bf(fast_tanhf(bl.x - ap[(k0 + 0) * 16]));
            t[1] = (short)f2bf(fast_tanhf(bl.y - ap[(k0 + 1) * 16]));
            t[2] = (short)f2bf(fast_tanhf(bl.z - ap[(k0 + 2) * 16]));
            t[3] = (short)f2bf(fast_tanhf(bl.w - ap[(k0 + 3) * 16]));
            t[4] = (short)f2bf(fast_tanhf(bh.x - ap[(k0 + 16) * 16]));
            t[5] = (short)f2bf(fast_tanhf(bh.y - ap[(k0 + 17) * 16]));
            t[6] = (short)f2bf(fast_tanhf(bh.z - ap[(k0 + 18) * 16]));
            t[7] = (short)f2bf(fast_tanhf(bh.w - ap[(k0 + 19) * 16]));
            e[vt][kc] = t;
        }
    }

    // Phase 2: MFMAs, Wrm fragments streamed from the lane-ordered table
    const short8v* wf = reinterpret_cast<const short8v*>(wfrag);
    f32x4 acc[4][2];
    #pragma unroll
    for (int ot = 0; ot < 4; ++ot) {
        acc[ot][0] = (f32x4){0.f, 0.f, 0.f, 0.f};
        acc[ot][1] = (f32x4){0.f, 0.f, 0.f, 0.f};
    }
    #pragma unroll
    for (int ot = 0; ot < 4; ++ot)
        #pragma unroll
        for (int kc = 0; kc < 4; ++kc) {
            short8v wv = wf[(ot * 4 + kc) * 64 + lane];
            acc[ot][0] = __builtin_amdgcn_mfma_f32_16x16x32_bf16(wv, e[0][kc], acc[ot][0], 0, 0, 0);
            acc[ot][1] = __builtin_amdgcn_mfma_f32_16x16x32_bf16(wv, e[1][kc], acc[ot][1], 0, 0, 0);
        }

    // acc -> LDS tile (C/D layout: row = 4g+r, col = l15) — verified round 3
    #pragma unroll
    for (int ot = 0; ot < 4; ++ot)
        #pragma unroll
        for (int vt = 0; vt < 2; ++vt)
            #pragma unroll
            for (int r = 0; r < 4; ++r)
                tile[ot * 16 + 4 * g + r][wid * 32 + vt * 16 + l15] = acc[ot][vt][r];
    __syncthreads();

    // coalesced dump: xmT[n][o][w][v] = brm[o] + AT[o][w][v] - tile[o][v]
    for (int i = tid; i < COUT_ * 64; i += 256) {
        int o = i >> 6, vp = i & 63;
        float t0 = tile[o][2 * vp], t1 = tile[o][2 * vp + 1];
        float2 at = *reinterpret_cast<const float2*>(
            AT + ((size_t)o * V_ + w) * V_ + 2 * vp);
        float br = brm[o];
        unsigned u = (unsigned)f2bf(br + at.x - t0)
                   | ((unsigned)f2bf(br + at.y - t1) << 16);
        reinterpret_cast<unsigned*>(xmT)[(((size_t)n * COUT_ + o) * V_ + w) * 64 + vp] = u;
    }
}

// ---------------------------------------------------------------------------
// k3: MFMA. Per block (n, t): out[c][w] = sum_v xf[c][v] * xmT[t][w][v].
// Both tiles LDS-staged with XOR swizzle; direct f32 stores.
// ---------------------------------------------------------------------------
__global__ __launch_bounds__(256) void k3_mfma(
    const unsigned short* __restrict__ xf,
    const unsigned short* __restrict__ xmT,
    float* __restrict__ out)
{
    __shared__ unsigned short xfl[COUT_ * V_];  // [c][v] swizzled, 16 KB
    __shared__ unsigned short xml[V_ * V_];     // [w][v] swizzled, 32 KB
    const int n = blockIdx.x, t = blockIdx.y;
    const int tid  = threadIdx.x;
    const int lane = tid & 63, wid = tid >> 6;
    const int l15  = lane & 15, g = lane >> 4;

    for (int i = tid; i < 1024; i += 256) {  // xf tile, 16B chunks
        int c = i >> 4, ch = i & 15;
        float4 d = *reinterpret_cast<const float4*>(
            xf + (((size_t)n * COUT_ + c) * T_ + t) * V_ + ch * 8);
        int dst = c * 256 + ((ch * 16) ^ ((c & 7) << 4));
        *reinterpret_cast<float4*>(reinterpret_cast<char*>(xfl) + dst) = d;
    }
    for (int i = tid; i < 2048; i += 256) {  // xm tile
        int wq = i >> 4, ch = i & 15;
        float4 d = *reinterpret_cast<const float4*>(
            xmT + (((size_t)n * COUT_ + t) * V_ + wq) * V_ + ch * 8);
        int dst = wq * 256 + ((ch * 16) ^ ((wq & 7) << 4));
        *reinterpret_cast<float4*>(reinterpret_cast<char*>(xml) + dst) = d;
    }
    __syncthreads();

    f32x4 acc[4][2];
    #pragma unroll
    for (int ct = 0; ct < 4; ++ct) {
        acc[ct][0] = (f32x4){0.f, 0.f, 0.f, 0.f};
        acc[ct][1] = (f32x4){0.f, 0.f, 0.f, 0.f};
    }

    #pragma unroll
    for (int kc = 0; kc < 4; ++kc) {
        const int vb0 = (kc * 32 + 4 * g) * 2;  // byte offset, half 0
        const int vb1 = vb0 + 32;               // +16 elements
        short8v af[4];
        #pragma unroll
        for (int ct = 0; ct < 4; ++ct) {
            int c = ct * 16 + l15, sw = (c & 7) << 4;
            short4v lo = *reinterpret_cast<const short4v*>(
                reinterpret_cast<const char*>(xfl) + c * 256 + (vb0 ^ sw));
            short4v hi = *reinterpret_cast<const short4v*>(
                reinterpret_cast<const char*>(xfl) + c * 256 + (vb1 ^ sw));
            af[ct] = __builtin_shufflevector(lo, hi, 0, 1, 2, 3, 4, 5, 6, 7);
        }
        short8v bg[2];
        #pragma unroll
        for (int wt = 0; wt < 2; ++wt) {
            int wq = wid * 32 + wt * 16 + l15, sw = (wq & 7) << 4;
            short4v lo = *reinterpret_cast<const short4v*>(
                reinterpret_cast<const char*>(xml) + wq * 256 + (vb0 ^ sw));
            short4v hi = *reinterpret_cast<const short4v*>(
                reinterpret_cast<const char*>(xml) + wq * 256 + (vb1 ^ sw));
            bg[wt] = __builtin_shufflevector(lo, hi, 0, 1, 2, 3, 4, 5, 6, 7);
        }
        #pragma unroll
        for (int ct = 0; ct < 4; ++ct)
            #pragma unroll
            for (int wt = 0; wt < 2; ++wt)
                acc[ct][wt] = __builtin_amdgcn_mfma_f32_16x16x32_bf16(
                    af[ct], bg[wt], acc[ct][wt], 0, 0, 0);
    }

    #pragma unroll
    for (int ct = 0; ct < 4; ++ct)
        #pragma unroll
        for (int wt = 0; wt < 2; ++wt)
            #pragma unroll
            for (int r = 0; r < 4; ++r) {
                int c = ct * 16 + 4 * g + r;
                int wcol = wid * 32 + wt * 16 + l15;
                out[(((size_t)n * COUT_ + c) * T_ + t) * V_ + wcol] = acc[ct][wt][r];
            }
}

extern "C" void kernel_launch(void* const* d_in, const int* in_sizes, int n_in,
                              void* d_out, int out_size, void* d_ws, size_t ws_size,
                              hipStream_t stream) {
    const float* x   = (const float*)d_in[0];
    const float* A   = (const float*)d_in[1];
    const float* Wf  = (const float*)d_in[2];
    const float* bf  = (const float*)d_in[3];
    const float* Wm1 = (const float*)d_in[4];
    const float* bm1 = (const float*)d_in[5];
    const float* Wm2 = (const float*)d_in[6];
    const float* bm2 = (const float*)d_in[7];
    const float* Wrm = (const float*)d_in[8];
    const float* brm = (const float*)d_in[9];
    float* out = (float*)d_out;

    char* ws = (char*)d_ws;
    unsigned short* xf = (unsigned short*)ws;                 // 32 MB
    size_t off = (size_t)N_ * COUT_ * T_ * V_ * 2;
    float* bT    = (float*)(ws + off); off += (size_t)N_ * V_ * K_ * 4;    // 2 MB
    float* a_til = (float*)(ws + off); off += (size_t)N_ * V_ * K_ * 4;    // 2 MB
    float* AT    = (float*)(ws + off); off += (size_t)COUT_ * V_ * V_ * 4; // 4 MB
    unsigned short* wfrag = (unsigned short*)(ws + off); off += 4 * 4 * 64 * 8 * 2; // 16 KB
    unsigned short* xmT = (unsigned short*)(ws + off);        // 64 MB

    k0_transpose_A<<<dim3(COUT_, 16), 256, 0, stream>>>(A, AT);
    k0b_wrm_frag<<<4, 256, 0, stream>>>(Wrm, wfrag);
    k1_conv<<<dim3(N_, (T_ * V_) / 256), 256, 0, stream>>>(
        x, Wf, bf, Wm1, bm1, Wm2, bm2, xf, a_til, bT);
    k2_mfma<<<dim3(N_, V_), 256, 0, stream>>>(a_til, bT, wfrag, brm, AT, xmT);
    k3_mfma<<<dim3(N_, T_), 256, 0, stream>>>(xf, xmT, out);
}

// Round 7
// 220.510 us; speedup vs baseline: 2.4620x; 1.2275x over previous
//
#include <hip/hip_runtime.h>
#include <hip/hip_bf16.h>

#define N_ 32
#define CIN_ 64
#define COUT_ 64
#define T_ 64
#define V_ 128
#define K_ 128  // RED_*T_

typedef __attribute__((ext_vector_type(8))) short short8v;  // 8 bf16 = 4 VGPR
typedef __attribute__((ext_vector_type(4))) short short4v;  // 4 bf16 = 2 VGPR
typedef __attribute__((ext_vector_type(4))) float f32x4;    // MFMA acc

__device__ __forceinline__ float fast_tanhf(float x) {
    // tanh(x) = 1 - 2/(exp(2x)+1); exact at +-inf, branch-free
    float e = __expf(2.0f * x);
    return 1.0f - 2.0f * __builtin_amdgcn_rcpf(e + 1.0f);
}
__device__ __forceinline__ unsigned short f2bf(float f) {
    __hip_bfloat16 h = __float2bfloat16(f);
    return *reinterpret_cast<unsigned short*>(&h);
}

// ---------------------------------------------------------------------------
// k0a: AT[o][w][v] = A[o][v][w]  (4 MB, tiled 32x32 LDS transpose)
// ---------------------------------------------------------------------------
__global__ __launch_bounds__(256) void k0_transpose_A(
    const float* __restrict__ A, float* __restrict__ AT)
{
    __shared__ float t[32][33];
    const int o  = blockIdx.x;
    const int v0 = (blockIdx.y >> 2) * 32, w0 = (blockIdx.y & 3) * 32;
    const float* Ao = A  + (size_t)o * (V_ * V_);
    float*      ATo = AT + (size_t)o * (V_ * V_);
    for (int i = threadIdx.x; i < 1024; i += 256) {
        int r = i >> 5, c = i & 31;
        t[r][c] = Ao[(v0 + r) * V_ + (w0 + c)];
    }
    __syncthreads();
    for (int i = threadIdx.x; i < 1024; i += 256) {
        int r = i >> 5, c = i & 31;
        ATo[(w0 + r) * V_ + (v0 + c)] = t[c][r];
    }
}

// ---------------------------------------------------------------------------
// k0b: Wrm -> lane-ordered bf16 A-fragment table (16 KB) for k2.
// Entry (ot,kc,lane): o = ot*16+l15, k(j) = kc*32 + 4g + j (j<4), +16 (j>=4).
// ---------------------------------------------------------------------------
__global__ __launch_bounds__(256) void k0b_wrm_frag(
    const float* __restrict__ Wrm, unsigned short* __restrict__ wfrag)
{
    const int ent = blockIdx.x * 256 + threadIdx.x;  // 1024 entries
    const int lane = ent & 63, kc = (ent >> 6) & 3, ot = ent >> 8;
    const int l15 = lane & 15, g = lane >> 4;
    const float* wr = Wrm + (size_t)(ot * 16 + l15) * K_ + kc * 32 + 4 * g;
    short8v f;
    #pragma unroll
    for (int j = 0; j < 4; ++j) f[j]     = (short)f2bf(wr[j]);
    #pragma unroll
    for (int j = 0; j < 4; ++j) f[4 + j] = (short)f2bf(wr[16 + j]);
    reinterpret_cast<short8v*>(wfrag)[ent] = f;
}

// ---------------------------------------------------------------------------
// k0c: {Wf | Wm1,Wm2} -> lane-ordered bf16 A-fragment table (10 KB) for k1.
// 5 row-tiles (ot) x 2 k-chunks (kc) x 64 lanes. ot<4: Wf rows ot*16+l15.
// ot==4: rows 0,1 = Wm1, rows 2,3 = Wm2, rows 4..15 = 0 (so a/b convs ride
// the same MFMAs as xf, output rows beyond 3 are zero).
// ---------------------------------------------------------------------------
__global__ __launch_bounds__(256) void k0c_wf_frag(
    const float* __restrict__ Wf, const float* __restrict__ Wm1,
    const float* __restrict__ Wm2, unsigned short* __restrict__ wffrag)
{
    const int ent = blockIdx.x * 256 + threadIdx.x;
    if (ent >= 640) return;
    const int lane = ent & 63, kc = (ent >> 6) & 1, ot = ent >> 7;
    const int l15 = lane & 15, g = lane >> 4;
    short8v f = (short8v){0, 0, 0, 0, 0, 0, 0, 0};
    const float* wr = nullptr;
    if (ot < 4)          wr = Wf  + (size_t)(ot * 16 + l15) * CIN_;
    else if (l15 < 2)    wr = Wm1 + (size_t)l15 * CIN_;
    else if (l15 < 4)    wr = Wm2 + (size_t)(l15 - 2) * CIN_;
    if (wr) {
        wr += kc * 32 + 4 * g;
        #pragma unroll
        for (int j = 0; j < 4; ++j) f[j]     = (short)f2bf(wr[j]);
        #pragma unroll
        for (int j = 0; j < 4; ++j) f[4 + j] = (short)f2bf(wr[16 + j]);
    }
    reinterpret_cast<short8v*>(wffrag)[ent] = f;
}

// ---------------------------------------------------------------------------
// k1: all three 1x1 convs as one MFMA GEMM. Per block (n, 256-col tv chunk):
// C[64+4 rows][256 tv] = {Wf;Wm1;Wm2}[rows][c] * x[c][tv].  No LDS.
// B-frags load directly from global: for fixed (g,j), 16 l15-lanes read 64
// contiguous bytes (coalesced); x is read exactly once globally.
// Outputs: xf bf16 [n][o][tv]; a_til[n][v>>4][k][v&15]; bT[n][w][k].
// ---------------------------------------------------------------------------
__global__ __launch_bounds__(256) void k1_mfma(
    const float* __restrict__ x,
    const unsigned short* __restrict__ wffrag,
    const float* __restrict__ bfv,
    const float* __restrict__ bm1, const float* __restrict__ bm2,
    unsigned short* __restrict__ xf, float* __restrict__ a_til,
    float* __restrict__ bT)
{
    const int n = blockIdx.x, tv0 = blockIdx.y * 256;
    const int tid = threadIdx.x, lane = tid & 63, wid = tid >> 6;
    const int l15 = lane & 15, g = lane >> 4;
    const float* xn = x + (size_t)n * (CIN_ * T_ * V_);
    const int colbase = tv0 + wid * 64 + l15;

    f32x4 acc[5][4];
    #pragma unroll
    for (int ot = 0; ot < 5; ++ot)
        #pragma unroll
        for (int nt = 0; nt < 4; ++nt)
            acc[ot][nt] = (f32x4){0.f, 0.f, 0.f, 0.f};

    const short8v* wf = reinterpret_cast<const short8v*>(wffrag);
    #pragma unroll
    for (int kc = 0; kc < 2; ++kc) {
        short8v bfrag[4];
        #pragma unroll
        for (int nt = 0; nt < 4; ++nt) {
            const float* xp = xn + (size_t)(kc * 32 + 4 * g) * (T_ * V_)
                            + colbase + nt * 16;
            short8v t;
            #pragma unroll
            for (int j = 0; j < 4; ++j)
                t[j]     = (short)f2bf(xp[(size_t)j * (T_ * V_)]);
            #pragma unroll
            for (int j = 0; j < 4; ++j)
                t[4 + j] = (short)f2bf(xp[(size_t)(16 + j) * (T_ * V_)]);
            bfrag[nt] = t;
        }
        #pragma unroll
        for (int ot = 0; ot < 5; ++ot) {
            short8v wv = wf[(ot * 2 + kc) * 64 + lane];
            #pragma unroll
            for (int nt = 0; nt < 4; ++nt)
                acc[ot][nt] = __builtin_amdgcn_mfma_f32_16x16x32_bf16(
                    wv, bfrag[nt], acc[ot][nt], 0, 0, 0);
        }
    }

    // xf epilogue: row o = ot*16+4g+r, col = colbase+nt*16 (C/D layout verified)
    #pragma unroll
    for (int ot = 0; ot < 4; ++ot) {
        float4 bias = *reinterpret_cast<const float4*>(bfv + ot * 16 + 4 * g);
        const float bi[4] = {bias.x, bias.y, bias.z, bias.w};
        #pragma unroll
        for (int nt = 0; nt < 4; ++nt) {
            const int col = colbase + nt * 16;
            #pragma unroll
            for (int r = 0; r < 4; ++r) {
                const int o = ot * 16 + 4 * g + r;
                xf[((size_t)n * COUT_ + o) * (T_ * V_) + col] =
                    f2bf(acc[ot][nt][r] + bi[r]);
            }
        }
    }

    // a/b epilogue: only g==0 lanes hold rows 0..3 of the Wm tile
    if (g == 0) {
        const float b10 = bm1[0], b11 = bm1[1], b20 = bm2[0], b21 = bm2[1];
        #pragma unroll
        for (int nt = 0; nt < 4; ++nt) {
            const int tv = colbase + nt * 16;
            const int t = tv >> 7, v = tv & 127;
            float* at = a_til + (((size_t)n * 8 + (v >> 4)) * K_) * 16 + (v & 15);
            at[(size_t)t * 16]        = acc[4][nt][0] + b10;
            at[(size_t)(64 + t) * 16] = acc[4][nt][1] + b11;
            float* btp = bT + ((size_t)n * V_ + v) * K_;
            btp[t]      = acc[4][nt][2] + b20;
            btp[64 + t] = acc[4][nt][3] + b21;
        }
    }
}

// ---------------------------------------------------------------------------
// k2: MFMA. Per block (n, w): C'[o][v] = sum_k Wrm[o][k] * tanh(b[k][w]-a[k][v])
// xmT[n][o][w][v] = brm[o] + A[o][v][w] - C'[o][v]   (tanh odd => sign trick).
// ---------------------------------------------------------------------------
__global__ __launch_bounds__(256) void k2_mfma(
    const float* __restrict__ a_til, const float* __restrict__ bT,
    const unsigned short* __restrict__ wfrag, const float* __restrict__ brm,
    const float* __restrict__ AT, unsigned short* __restrict__ xmT)
{
    __shared__ float tile[COUT_][V_ + 1];
    const int n = blockIdx.x, w = blockIdx.y;
    const int tid  = threadIdx.x;
    const int lane = tid & 63, wid = tid >> 6;
    const int l15  = lane & 15, g = lane >> 4;

    const float* bt = bT + ((size_t)n * V_ + w) * K_;
    const float* abase = a_til + (size_t)n * 16384 + l15;

    short8v e[2][4];
    #pragma unroll
    for (int vt = 0; vt < 2; ++vt) {
        const float* ap = abase + (size_t)(wid * 2 + vt) * 2048;
        #pragma unroll
        for (int kc = 0; kc < 4; ++kc) {
            const int k0 = kc * 32 + 4 * g;
            float4 bl = *reinterpret_cast<const float4*>(bt + k0);
            float4 bh = *reinterpret_cast<const float4*>(bt + k0 + 16);
            short8v t;
            t[0] = (short)f2bf(fast_tanhf(bl.x - ap[(k0 + 0) * 16]));
            t[1] = (short)f2bf(fast_tanhf(bl.y - ap[(k0 + 1) * 16]));
            t[2] = (short)f2bf(fast_tanhf(bl.z - ap[(k0 + 2) * 16]));
            t[3] = (short)f2bf(fast_tanhf(bl.w - ap[(k0 + 3) * 16]));
            t[4] = (short)f2bf(fast_tanhf(bh.x - ap[(k0 + 16) * 16]));
            t[5] = (short)f2bf(fast_tanhf(bh.y - ap[(k0 + 17) * 16]));
            t[6] = (short)f2bf(fast_tanhf(bh.z - ap[(k0 + 18) * 16]));
            t[7] = (short)f2bf(fast_tanhf(bh.w - ap[(k0 + 19) * 16]));
            e[vt][kc] = t;
        }
    }

    const short8v* wf = reinterpret_cast<const short8v*>(wfrag);
    f32x4 acc[4][2];
    #pragma unroll
    for (int ot = 0; ot < 4; ++ot) {
        acc[ot][0] = (f32x4){0.f, 0.f, 0.f, 0.f};
        acc[ot][1] = (f32x4){0.f, 0.f, 0.f, 0.f};
    }
    #pragma unroll
    for (int ot = 0; ot < 4; ++ot)
        #pragma unroll
        for (int kc = 0; kc < 4; ++kc) {
            short8v wv = wf[(ot * 4 + kc) * 64 + lane];
            acc[ot][0] = __builtin_amdgcn_mfma_f32_16x16x32_bf16(wv, e[0][kc], acc[ot][0], 0, 0, 0);
            acc[ot][1] = __builtin_amdgcn_mfma_f32_16x16x32_bf16(wv, e[1][kc], acc[ot][1], 0, 0, 0);
        }

    #pragma unroll
    for (int ot = 0; ot < 4; ++ot)
        #pragma unroll
        for (int vt = 0; vt < 2; ++vt)
            #pragma unroll
            for (int r = 0; r < 4; ++r)
                tile[ot * 16 + 4 * g + r][wid * 32 + vt * 16 + l15] = acc[ot][vt][r];
    __syncthreads();

    for (int i = tid; i < COUT_ * 64; i += 256) {
        int o = i >> 6, vp = i & 63;
        float t0 = tile[o][2 * vp], t1 = tile[o][2 * vp + 1];
        float2 at = *reinterpret_cast<const float2*>(
            AT + ((size_t)o * V_ + w) * V_ + 2 * vp);
        float br = brm[o];
        unsigned u = (unsigned)f2bf(br + at.x - t0)
                   | ((unsigned)f2bf(br + at.y - t1) << 16);
        reinterpret_cast<unsigned*>(xmT)[(((size_t)n * COUT_ + o) * V_ + w) * 64 + vp] = u;
    }
}

// ---------------------------------------------------------------------------
// k3: MFMA. Per block (n, t): out[c][w] = sum_v xf[c][v] * xmT[t][w][v].
// ---------------------------------------------------------------------------
__global__ __launch_bounds__(256) void k3_mfma(
    const unsigned short* __restrict__ xf,
    const unsigned short* __restrict__ xmT,
    float* __restrict__ out)
{
    __shared__ unsigned short xfl[COUT_ * V_];
    __shared__ unsigned short xml[V_ * V_];
    const int n = blockIdx.x, t = blockIdx.y;
    const int tid  = threadIdx.x;
    const int lane = tid & 63, wid = tid >> 6;
    const int l15  = lane & 15, g = lane >> 4;

    for (int i = tid; i < 1024; i += 256) {
        int c = i >> 4, ch = i & 15;
        float4 d = *reinterpret_cast<const float4*>(
            xf + (((size_t)n * COUT_ + c) * T_ + t) * V_ + ch * 8);
        int dst = c * 256 + ((ch * 16) ^ ((c & 7) << 4));
        *reinterpret_cast<float4*>(reinterpret_cast<char*>(xfl) + dst) = d;
    }
    for (int i = tid; i < 2048; i += 256) {
        int wq = i >> 4, ch = i & 15;
        float4 d = *reinterpret_cast<const float4*>(
            xmT + (((size_t)n * COUT_ + t) * V_ + wq) * V_ + ch * 8);
        int dst = wq * 256 + ((ch * 16) ^ ((wq & 7) << 4));
        *reinterpret_cast<float4*>(reinterpret_cast<char*>(xml) + dst) = d;
    }
    __syncthreads();

    f32x4 acc[4][2];
    #pragma unroll
    for (int ct = 0; ct < 4; ++ct) {
        acc[ct][0] = (f32x4){0.f, 0.f, 0.f, 0.f};
        acc[ct][1] = (f32x4){0.f, 0.f, 0.f, 0.f};
    }

    #pragma unroll
    for (int kc = 0; kc < 4; ++kc) {
        const int vb0 = (kc * 32 + 4 * g) * 2;
        const int vb1 = vb0 + 32;
        short8v af[4];
        #pragma unroll
        for (int ct = 0; ct < 4; ++ct) {
            int c = ct * 16 + l15, sw = (c & 7) << 4;
            short4v lo = *reinterpret_cast<const short4v*>(
                reinterpret_cast<const char*>(xfl) + c * 256 + (vb0 ^ sw));
            short4v hi = *reinterpret_cast<const short4v*>(
                reinterpret_cast<const char*>(xfl) + c * 256 + (vb1 ^ sw));
            af[ct] = __builtin_shufflevector(lo, hi, 0, 1, 2, 3, 4, 5, 6, 7);
        }
        short8v bg[2];
        #pragma unroll
        for (int wt = 0; wt < 2; ++wt) {
            int wq = wid * 32 + wt * 16 + l15, sw = (wq & 7) << 4;
            short4v lo = *reinterpret_cast<const short4v*>(
                reinterpret_cast<const char*>(xml) + wq * 256 + (vb0 ^ sw));
            short4v hi = *reinterpret_cast<const short4v*>(
                reinterpret_cast<const char*>(xml) + wq * 256 + (vb1 ^ sw));
            bg[wt] = __builtin_shufflevector(lo, hi, 0, 1, 2, 3, 4, 5, 6, 7);
        }
        #pragma unroll
        for (int ct = 0; ct < 4; ++ct)
            #pragma unroll
            for (int wt = 0; wt < 2; ++wt)
                acc[ct][wt] = __builtin_amdgcn_mfma_f32_16x16x32_bf16(
                    af[ct], bg[wt], acc[ct][wt], 0, 0, 0);
    }

    #pragma unroll
    for (int ct = 0; ct < 4; ++ct)
        #pragma unroll
        for (int wt = 0; wt < 2; ++wt)
            #pragma unroll
            for (int r = 0; r < 4; ++r) {
                int c = ct * 16 + 4 * g + r;
                int wcol = wid * 32 + wt * 16 + l15;
                out[(((size_t)n * COUT_ + c) * T_ + t) * V_ + wcol] = acc[ct][wt][r];
            }
}

extern "C" void kernel_launch(void* const* d_in, const int* in_sizes, int n_in,
                              void* d_out, int out_size, void* d_ws, size_t ws_size,
                              hipStream_t stream) {
    const float* x   = (const float*)d_in[0];
    const float* A   = (const float*)d_in[1];
    const float* Wf  = (const float*)d_in[2];
    const float* bf  = (const float*)d_in[3];
    const float* Wm1 = (const float*)d_in[4];
    const float* bm1 = (const float*)d_in[5];
    const float* Wm2 = (const float*)d_in[6];
    const float* bm2 = (const float*)d_in[7];
    const float* Wrm = (const float*)d_in[8];
    const float* brm = (const float*)d_in[9];
    float* out = (float*)d_out;

    char* ws = (char*)d_ws;
    unsigned short* xf = (unsigned short*)ws;                 // 32 MB
    size_t off = (size_t)N_ * COUT_ * T_ * V_ * 2;
    float* bT    = (float*)(ws + off); off += (size_t)N_ * V_ * K_ * 4;    // 2 MB
    float* a_til = (float*)(ws + off); off += (size_t)N_ * V_ * K_ * 4;    // 2 MB
    float* AT    = (float*)(ws + off); off += (size_t)COUT_ * V_ * V_ * 4; // 4 MB
    unsigned short* wfrag  = (unsigned short*)(ws + off); off += 4 * 4 * 64 * 8 * 2; // 16 KB
    unsigned short* wffrag = (unsigned short*)(ws + off); off += 5 * 2 * 64 * 8 * 2; // 10 KB
    unsigned short* xmT = (unsigned short*)(ws + off);        // 64 MB

    k0_transpose_A<<<dim3(COUT_, 16), 256, 0, stream>>>(A, AT);
    k0b_wrm_frag<<<4, 256, 0, stream>>>(Wrm, wfrag);
    k0c_wf_frag<<<3, 256, 0, stream>>>(Wf, Wm1, Wm2, wffrag);
    k1_mfma<<<dim3(N_, (T_ * V_) / 256), 256, 0, stream>>>(
        x, wffrag, bf, bm1, bm2, xf, a_til, bT);
    k2_mfma<<<dim3(N_, V_), 256, 0, stream>>>(a_til, bT, wfrag, brm, AT, xmT);
    k3_mfma<<<dim3(N_, T_), 256, 0, stream>>>(xf, xmT, out);
}